// Round 4
// baseline (217.723 us; speedup 1.0000x reference)
//
#include <hip/hip_runtime.h>

#define N_NODES 50000
#define N_EDGES 800000
#define IN_CH 128
#define HID_CH 256
#define OUT_CH 128
#define BUCKET 64  // max degree slot count; P(deg>64) ~ e^-40 for Poisson(16)

using half8 = __attribute__((ext_vector_type(8))) _Float16;
using f32x4 = __attribute__((ext_vector_type(4))) float;

// ---------------- three-phase bucket build ----------------
// Phase A: block-local LDS histogram over 391 bins (bin = dst>>7, 128 nodes/bin),
//          ONE global atomic per (block,bin) to reserve space, scatter packed
//          (src | dlocal<<16) into bin segments.
// Phase B: one block per bin; slot assignment via LDS atomicAdd (on-CU); src-only
//          bucket rows assembled in zero-initialized LDS, streamed out as uint2
//          {src,0} coalesced; writes true cnt[] directly.
// Phase C: streaming pass packs w = rsqrt(cnt[src]+1) (fp32, bit-exact vs old
//          in-loop compute) into .y of every slot. Removes the dependent
//          cnt-gather + rsqrt from BOTH agg layers' critical paths.

#define NB 391        // bins = ceil(50000/128); 49999>>7 = 390
#define NPB 128       // nodes per bin
#define BIN_CAP 2432  // per-bin record capacity: mu=2048, sigma~45 -> mu+8.5sigma
#define A_CHUNK 4096  // edges per phase-A block
#define A_BLOCKS 196  // ceil(800000/4096)
#define NSLOTS (NB * NPB * BUCKET)       // 3,203,072 padded bucket slots
#define C_BLOCKS (NSLOTS / 512)          // 6256: 2 slots/thread via uint4

#define CVT_BLOCKS 3125  // 50000*128/8 half8 items / 256
#define WT1_BLOCKS 256   // HID_CH rows of W1T
#define WT2_BLOCKS 128   // OUT_CH rows of W2T

__global__ __launch_bounds__(256) void prepA_kernel(const int* __restrict__ src,
                                                    const int* __restrict__ dst,
                                                    int* __restrict__ bin_fill,
                                                    unsigned int* __restrict__ binbuf,
                                                    const float* __restrict__ x,
                                                    _Float16* __restrict__ x16,
                                                    const float* __restrict__ W1,
                                                    _Float16* __restrict__ W1T,
                                                    const float* __restrict__ W2,
                                                    _Float16* __restrict__ W2T) {
    __shared__ int hist[NB];
    __shared__ int lbase[NB];
    __shared__ int cur[NB];
    int b = blockIdx.x, t = threadIdx.x;
    if (b < A_BLOCKS) {
        for (int i = t; i < NB; i += 256) {
            hist[i] = 0;
            cur[i] = 0;
        }
        __syncthreads();
        int e0 = b * A_CHUNK;
        int d[16];
#pragma unroll
        for (int k = 0; k < 16; k++) {
            int i = e0 + k * 256 + t;
            d[k] = (i < N_EDGES) ? dst[i] : -1;
            if (d[k] >= 0) atomicAdd(&hist[d[k] >> 7], 1);
        }
        __syncthreads();
        for (int i = t; i < NB; i += 256)
            if (hist[i]) lbase[i] = atomicAdd(&bin_fill[i], hist[i]);
        __syncthreads();
#pragma unroll
        for (int k = 0; k < 16; k++) {
            int i = e0 + k * 256 + t;
            if (d[k] >= 0) {
                int bin = d[k] >> 7;
                int s = src[i];
                int o = atomicAdd(&cur[bin], 1);
                int pos = lbase[bin] + o;
                if (pos < BIN_CAP)
                    binbuf[(size_t)bin * BIN_CAP + pos] =
                        (unsigned)s | ((unsigned)(d[k] & (NPB - 1)) << 16);
            }
        }
    } else if (b < A_BLOCKS + CVT_BLOCKS) {
        int i = (b - A_BLOCKS) * 256 + t;  // half8 index
        float4 v0 = ((const float4*)x)[i * 2];
        float4 v1 = ((const float4*)x)[i * 2 + 1];
        half8 o = {(_Float16)v0.x, (_Float16)v0.y, (_Float16)v0.z, (_Float16)v0.w,
                   (_Float16)v1.x, (_Float16)v1.y, (_Float16)v1.z, (_Float16)v1.w};
        ((half8*)x16)[i] = o;
    } else if (b < A_BLOCKS + CVT_BLOCKS + WT1_BLOCKS) {
        int n = b - A_BLOCKS - CVT_BLOCKS;
        if (t < IN_CH) W1T[(size_t)n * IN_CH + t] = (_Float16)W1[(size_t)t * HID_CH + n];
    } else {
        int n = b - A_BLOCKS - CVT_BLOCKS - WT1_BLOCKS;
        if (t < HID_CH) W2T[(size_t)n * HID_CH + t] = (_Float16)W2[(size_t)t * OUT_CH + n];
    }
}

__global__ __launch_bounds__(256) void prepB_kernel(const int* __restrict__ bin_fill,
                                                    const unsigned int* __restrict__ binbuf,
                                                    int* __restrict__ cnt,
                                                    uint2* __restrict__ bucket) {
    __shared__ int lcnt[NPB];
    __shared__ __align__(16) unsigned int lbx[NPB][BUCKET];  // src ids, 32 KB
    int bin = blockIdx.x, t = threadIdx.x;
    if (t < NPB) lcnt[t] = 0;
    for (int q = t; q < NPB * BUCKET / 4; q += 256)
        ((uint4*)lbx)[q] = make_uint4(0u, 0u, 0u, 0u);  // empty slots -> src 0 (safe)
    __syncthreads();
    int n = min(bin_fill[bin], BIN_CAP);
    for (int i = t; i < n; i += 256) {
        unsigned e = binbuf[(size_t)bin * BIN_CAP + i];
        int dl = e >> 16;
        unsigned s = e & 0xFFFFu;
        int p = atomicAdd(&lcnt[dl], 1);
        if (p < BUCKET) lbx[dl][p] = s;
    }
    __syncthreads();
    // stream out coalesced: slot q -> {src, 0}; prepC fills .y
    const unsigned* lp = (const unsigned*)lbx;
    uint2* gp = bucket + (size_t)bin * NPB * BUCKET;
    for (int q = t; q < NPB * BUCKET; q += 256) gp[q] = make_uint2(lp[q], 0u);
    int v = bin * NPB + t;
    if (t < NPB && v < N_NODES) cnt[v] = lcnt[t];
}

// Phase C: pack per-edge norm weight w = rsqrt(cnt[src]+1) into slot .y.
// cnt table is 200 KB (L2-resident); fully streaming uint4 in/out.
__global__ __launch_bounds__(256) void prepC_kernel(const int* __restrict__ cnt,
                                                    uint2* __restrict__ bucket) {
    int i = blockIdx.x * 256 + threadIdx.x;
    uint4 e = ((uint4*)bucket)[i];
    e.y = __float_as_uint(rsqrtf((float)cnt[e.x] + 1.0f));
    e.w = __float_as_uint(rsqrtf((float)cnt[e.z] + 1.0f));
    ((uint4*)bucket)[i] = e;
}

// ---------------- aggregation (fp16 features, 128 ch) ----------------
// 16 lanes per node, 8 ch per lane; neighbor ids broadcast via shfl(width=16).
// Inner loop: ONE 8B load per edge slot {src, w} -> shfl -> gather -> FMA.
// (Previously: bucket load -> dependent cnt[src] gather -> rsqrt -> shfl -> gather;
// one full L2 round-trip longer per chunk, recomputed per layer.)
// Dummy lanes (idx >= deg) force a=0 BEFORE the gather and w=0 (NaN-safe).

template <bool OUT16>
__global__ __launch_bounds__(256) void agg16_kernel(const _Float16* __restrict__ h16,
                                                    const int* __restrict__ cnt,
                                                    const uint2* __restrict__ bucket,
                                                    const float* __restrict__ bias,
                                                    void* __restrict__ outp) {
    int t = blockIdx.x * 256 + threadIdx.x;
    int v = t >> 4;      // node (grid sized exactly: 50000*16/256 blocks)
    int sub = t & 15;    // lane group index
    int degr = cnt[v];
    int deg = min(degr, BUCKET);  // loop bound (UB guard; real max deg ~35)
    float dv = rsqrtf((float)degr + 1.0f);
    half8 hv = ((const half8*)(h16 + (size_t)v * 128))[sub];
    float acc[8];
#pragma unroll
    for (int i = 0; i < 8; i++) acc[i] = (float)hv[i] * dv * dv;  // self-loop

#define PROCESS8(J)                                                                   \
    {                                                                                 \
        int   s0 = __shfl(a, (J) + 0, 16); float w0 = __shfl(c, (J) + 0, 16);         \
        int   s1 = __shfl(a, (J) + 1, 16); float w1 = __shfl(c, (J) + 1, 16);         \
        int   s2 = __shfl(a, (J) + 2, 16); float w2 = __shfl(c, (J) + 2, 16);         \
        int   s3 = __shfl(a, (J) + 3, 16); float w3 = __shfl(c, (J) + 3, 16);         \
        int   s4 = __shfl(a, (J) + 4, 16); float w4 = __shfl(c, (J) + 4, 16);         \
        int   s5 = __shfl(a, (J) + 5, 16); float w5 = __shfl(c, (J) + 5, 16);         \
        int   s6 = __shfl(a, (J) + 6, 16); float w6 = __shfl(c, (J) + 6, 16);         \
        int   s7 = __shfl(a, (J) + 7, 16); float w7 = __shfl(c, (J) + 7, 16);         \
        half8 x0 = ((const half8*)(h16 + (size_t)s0 * 128))[sub];                     \
        half8 x1 = ((const half8*)(h16 + (size_t)s1 * 128))[sub];                     \
        half8 x2 = ((const half8*)(h16 + (size_t)s2 * 128))[sub];                     \
        half8 x3 = ((const half8*)(h16 + (size_t)s3 * 128))[sub];                     \
        half8 x4 = ((const half8*)(h16 + (size_t)s4 * 128))[sub];                     \
        half8 x5 = ((const half8*)(h16 + (size_t)s5 * 128))[sub];                     \
        half8 x6 = ((const half8*)(h16 + (size_t)s6 * 128))[sub];                     \
        half8 x7 = ((const half8*)(h16 + (size_t)s7 * 128))[sub];                     \
        _Pragma("unroll") for (int i = 0; i < 8; i++) acc[i] += w0 * (float)x0[i];    \
        _Pragma("unroll") for (int i = 0; i < 8; i++) acc[i] += w1 * (float)x1[i];    \
        _Pragma("unroll") for (int i = 0; i < 8; i++) acc[i] += w2 * (float)x2[i];    \
        _Pragma("unroll") for (int i = 0; i < 8; i++) acc[i] += w3 * (float)x3[i];    \
        _Pragma("unroll") for (int i = 0; i < 8; i++) acc[i] += w4 * (float)x4[i];    \
        _Pragma("unroll") for (int i = 0; i < 8; i++) acc[i] += w5 * (float)x5[i];    \
        _Pragma("unroll") for (int i = 0; i < 8; i++) acc[i] += w6 * (float)x6[i];    \
        _Pragma("unroll") for (int i = 0; i < 8; i++) acc[i] += w7 * (float)x7[i];    \
    }

    const uint2* bk = bucket + (size_t)v * BUCKET;
    for (int base = 0; base < deg; base += 16) {
        int idx = base + sub;
        uint2 e = bk[min(idx, BUCKET - 1)];  // in-row clamp; one 8B load per slot
        bool ok = idx < deg;
        int a = ok ? (int)e.x : 0;           // mask BEFORE gather (NaN-safe)
        float c = ok ? __uint_as_float(e.y) * dv : 0.f;
        PROCESS8(0)
        if (base + 8 < deg) PROCESS8(8)
    }
#undef PROCESS8

    if (OUT16) {
        half8 o;
#pragma unroll
        for (int i = 0; i < 8; i++) o[i] = (_Float16)acc[i];
        ((half8*)outp)[(size_t)v * 16 + sub] = o;
    } else {
        const float4* bp = (const float4*)bias;
        float4 b0 = bp[sub * 2], b1v = bp[sub * 2 + 1];
        float4 o0 = make_float4(acc[0] + b0.x, acc[1] + b0.y, acc[2] + b0.z, acc[3] + b0.w);
        float4 o1 = make_float4(acc[4] + b1v.x, acc[5] + b1v.y, acc[6] + b1v.z, acc[7] + b1v.w);
        float4* op = (float4*)outp;
        op[(size_t)v * 32 + sub * 2] = o0;
        op[(size_t)v * 32 + sub * 2 + 1] = o1;
    }
}

// ---------------- fused MLP: t2 = relu(a1 @ W1 + b1) @ W2, fp16 in/out ----------------
// W1T/W2T are 64 KB each and L2-resident -> B fragments loaded per-wave directly
// from global (no Bs staging, 3 barriers/block). LDS = 50 KB -> 3 blocks/CU.

__global__ __launch_bounds__(256) void fused_mlp_kernel(const _Float16* __restrict__ A,
                                                        const _Float16* __restrict__ W1T,
                                                        const float* __restrict__ b1,
                                                        const _Float16* __restrict__ W2T,
                                                        _Float16* __restrict__ T2, int M) {
    const int LDH = 264;  // h1s row stride (256+8): row step = 4 banks -> 2-way only (free)
    const int LDA = 136;  // As/Cs row stride (128+8)
    __shared__ __align__(16) _Float16 h1s[64 * LDH];  // 33792 B
    __shared__ __align__(16) _Float16 As[64 * LDA];   // 17408 B; reused as Cs in epilogue

    int tid = threadIdx.x;
    int wave = tid >> 6, lane = tid & 63;
    int quad = lane >> 4, l16 = lane & 15;
    int wm = wave >> 1, wn = wave & 1;
    int bm = blockIdx.x * 64;

    // stage full A tile: 64 rows x 128 fp16
    for (int q = tid; q < 64 * 16; q += 256) {
        int row = q >> 4, seg = q & 15;
        int gr = bm + row;
        float4 v = make_float4(0.f, 0.f, 0.f, 0.f);
        if (gr < M) v = *(const float4*)(A + (size_t)gr * IN_CH + seg * 8);
        *(float4*)(As + row * LDA + seg * 8) = v;
    }
    __syncthreads();

    // ---- phase 1: h1 = relu(A @ W1T^T + b1), two N-halves of 128, no barriers ----
    for (int nh = 0; nh < 2; nh++) {
        f32x4 acc[2][4] = {};
#pragma unroll
        for (int k0 = 0; k0 < IN_CH; k0 += 32) {
            half8 af[2], bf[4];
#pragma unroll
            for (int nt = 0; nt < 4; nt++)
                bf[nt] = *(const half8*)(W1T + (size_t)(nh * 128 + wn * 64 + nt * 16 + l16) * IN_CH +
                                         k0 + quad * 8);
#pragma unroll
            for (int mt = 0; mt < 2; mt++)
                af[mt] = *(const half8*)(As + (wm * 32 + mt * 16 + l16) * LDA + k0 + quad * 8);
#pragma unroll
            for (int mt = 0; mt < 2; mt++)
#pragma unroll
                for (int nt = 0; nt < 4; nt++)
                    acc[mt][nt] = __builtin_amdgcn_mfma_f32_16x16x32_f16(af[mt], bf[nt], acc[mt][nt], 0, 0, 0);
        }
        // epilogue half -> h1s (relu + b1)
#pragma unroll
        for (int mt = 0; mt < 2; mt++)
#pragma unroll
            for (int nt = 0; nt < 4; nt++)
#pragma unroll
                for (int r = 0; r < 4; r++) {
                    int ml = wm * 32 + mt * 16 + quad * 4 + r;
                    int nl = wn * 64 + nt * 16 + l16;
                    float v = acc[mt][nt][r] + b1[nh * 128 + nl];
                    h1s[ml * LDH + nh * 128 + nl] = (_Float16)fmaxf(v, 0.f);
                }
    }
    __syncthreads();  // h1s complete before phase-2 reads

    // ---- phase 2: t2 = h1 @ W2T^T (K = 256: A from LDS, B from global) ----
    f32x4 acc2[2][4] = {};
#pragma unroll 4
    for (int k0 = 0; k0 < HID_CH; k0 += 32) {
        half8 af[2], bf[4];
#pragma unroll
        for (int nt = 0; nt < 4; nt++)
            bf[nt] = *(const half8*)(W2T + (size_t)(wn * 64 + nt * 16 + l16) * HID_CH + k0 + quad * 8);
#pragma unroll
        for (int mt = 0; mt < 2; mt++)
            af[mt] = *(const half8*)(h1s + (wm * 32 + mt * 16 + l16) * LDH + k0 + quad * 8);
#pragma unroll
        for (int mt = 0; mt < 2; mt++)
#pragma unroll
            for (int nt = 0; nt < 4; nt++)
                acc2[mt][nt] = __builtin_amdgcn_mfma_f32_16x16x32_f16(af[mt], bf[nt], acc2[mt][nt], 0, 0, 0);
    }

    // epilogue: t2 via Cs (= As region, free after phase 1) for coalesced fp16 stores
    _Float16* Cs = As;
#pragma unroll
    for (int mt = 0; mt < 2; mt++)
#pragma unroll
        for (int nt = 0; nt < 4; nt++)
#pragma unroll
            for (int r = 0; r < 4; r++) {
                int ml = wm * 32 + mt * 16 + quad * 4 + r;
                int nl = wn * 64 + nt * 16 + l16;
                Cs[ml * LDA + nl] = (_Float16)acc2[mt][nt][r];
            }
    __syncthreads();
    for (int q = tid; q < 64 * 16; q += 256) {
        int row = q >> 4, seg = q & 15;
        int gr = bm + row;
        if (gr < M)
            *(float4*)(T2 + (size_t)gr * OUT_CH + seg * 8) = *(const float4*)(Cs + row * LDA + seg * 8);
    }
}

// ---------------- launch ----------------

extern "C" void kernel_launch(void* const* d_in, const int* in_sizes, int n_in,
                              void* d_out, int out_size, void* d_ws, size_t ws_size,
                              hipStream_t stream) {
    const float* x  = (const float*)d_in[0];
    const int*   ei = (const int*)d_in[1];
    const int*   src = ei;
    const int*   dst = ei + N_EDGES;
    const float* W1 = (const float*)d_in[2];
    const float* b1 = (const float*)d_in[3];
    const float* W2 = (const float*)d_in[4];
    const float* b2 = (const float*)d_in[5];
    float* out = (float*)d_out;

    char* w = (char*)d_ws;
    auto alloc = [&](size_t bytes) -> void* {
        void* p = (void*)w;
        w += (bytes + 255) & ~(size_t)255;
        return p;
    };
    int*            cnt     = (int*)alloc((size_t)N_NODES * 4);
    uint2*          bucket  = (uint2*)alloc((size_t)NSLOTS * 8);  // padded {src,w} slots
    _Float16*       x16     = (_Float16*)alloc((size_t)N_NODES * IN_CH * 2);
    _Float16*       a1      = (_Float16*)alloc((size_t)N_NODES * IN_CH * 2);
    _Float16*       t2      = (_Float16*)alloc((size_t)N_NODES * OUT_CH * 2);
    _Float16*       W1T     = (_Float16*)alloc((size_t)IN_CH * HID_CH * 2);
    _Float16*       W2T     = (_Float16*)alloc((size_t)HID_CH * OUT_CH * 2);
    int*            bin_fill = (int*)alloc((size_t)NB * 4);
    unsigned int*   binbuf   = (unsigned int*)alloc((size_t)NB * BIN_CAP * 4);

    hipMemsetAsync(bin_fill, 0, (size_t)NB * 4, stream);

    // phase A: radix-partition edges into 391 bins (+ x->fp16 cvt + W transposes)
    prepA_kernel<<<A_BLOCKS + CVT_BLOCKS + WT1_BLOCKS + WT2_BLOCKS, 256, 0, stream>>>(
        src, dst, bin_fill, binbuf, x, x16, W1, W1T, W2, W2T);
    // phase B: per-bin bucket build (src-only), LDS-staged -> coalesced uint2 stores
    prepB_kernel<<<NB, 256, 0, stream>>>(bin_fill, binbuf, cnt, bucket);
    // phase C: pack per-edge weights (used by BOTH agg layers)
    prepC_kernel<<<C_BLOCKS, 256, 0, stream>>>(cnt, bucket);

    // layer 1 aggregate: a1 = Â x
    agg16_kernel<true><<<N_NODES * 16 / 256, 256, 0, stream>>>(x16, cnt, bucket, nullptr, a1);
    // fused MLP: t2 = relu(a1 @ W1 + b1) @ W2
    fused_mlp_kernel<<<(N_NODES + 63) / 64, 256, 0, stream>>>(a1, W1T, b1, W2T, t2, N_NODES);
    // layer 2 aggregate: out = Â t2 + b2
    agg16_kernel<false><<<N_NODES * 16 / 256, 256, 0, stream>>>(t2, cnt, bucket, b2, out);
}

// Round 5
// 214.587 us; speedup vs baseline: 1.0146x; 1.0146x over previous
//
#include <hip/hip_runtime.h>

#define N_NODES 50000
#define N_EDGES 800000
#define IN_CH 128
#define HID_CH 256
#define OUT_CH 128
#define BUCKET 64  // max degree slot count; P(deg>64) ~ e^-40 for Poisson(16)

using half8 = __attribute__((ext_vector_type(8))) _Float16;
using f32x4 = __attribute__((ext_vector_type(4))) float;

// ---------------- two-phase radix-partition bucket build ----------------
// Phase A: block-local LDS histogram over 391 bins (bin = dst>>7, 128 nodes/bin),
//          ONE global atomic per (block,bin) to reserve space, scatter packed
//          (src | dlocal<<16) into bin segments.
// Phase B: one block per bin; slot assignment via LDS atomicAdd (on-CU); bucket
//          rows assembled in LDS, streamed out as coalesced uint4 stores.
// (R4's uint2{src,w} + prepC variant REVERTED: +50MB traffic cost +12us at the
//  measured ~4.2 TB/s marginal rate; the in-loop cnt gather it removed is
//  L2-hot and ~free. Bytes are the binding constraint.)

#define NB 391        // bins = ceil(50000/128); 49999>>7 = 390
#define NPB 128       // nodes per bin
#define BIN_CAP 2432  // per-bin record capacity: mu=2048, sigma~45 -> mu+8.5sigma
#define A_CHUNK 4096  // edges per phase-A block
#define A_BLOCKS 196  // ceil(800000/4096)

#define CVT_BLOCKS 3125  // 50000*128/8 half8 items / 256
#define WT1_BLOCKS 256   // HID_CH rows of W1T
#define WT2_BLOCKS 128   // OUT_CH rows of W2T

__global__ __launch_bounds__(256) void prepA_kernel(const int* __restrict__ src,
                                                    const int* __restrict__ dst,
                                                    int* __restrict__ bin_fill,
                                                    unsigned int* __restrict__ binbuf,
                                                    const float* __restrict__ x,
                                                    _Float16* __restrict__ x16,
                                                    const float* __restrict__ W1,
                                                    _Float16* __restrict__ W1T,
                                                    const float* __restrict__ W2,
                                                    _Float16* __restrict__ W2T) {
    __shared__ int hist[NB];
    __shared__ int lbase[NB];
    __shared__ int cur[NB];
    int b = blockIdx.x, t = threadIdx.x;
    if (b < A_BLOCKS) {
        for (int i = t; i < NB; i += 256) {
            hist[i] = 0;
            cur[i] = 0;
        }
        __syncthreads();
        int e0 = b * A_CHUNK;
        int d[16];
#pragma unroll
        for (int k = 0; k < 16; k++) {
            int i = e0 + k * 256 + t;
            d[k] = (i < N_EDGES) ? dst[i] : -1;
            if (d[k] >= 0) atomicAdd(&hist[d[k] >> 7], 1);
        }
        __syncthreads();
        for (int i = t; i < NB; i += 256)
            if (hist[i]) lbase[i] = atomicAdd(&bin_fill[i], hist[i]);
        __syncthreads();
#pragma unroll
        for (int k = 0; k < 16; k++) {
            int i = e0 + k * 256 + t;
            if (d[k] >= 0) {
                int bin = d[k] >> 7;
                int s = src[i];
                int o = atomicAdd(&cur[bin], 1);
                int pos = lbase[bin] + o;
                if (pos < BIN_CAP)
                    binbuf[(size_t)bin * BIN_CAP + pos] =
                        (unsigned)s | ((unsigned)(d[k] & (NPB - 1)) << 16);
            }
        }
    } else if (b < A_BLOCKS + CVT_BLOCKS) {
        int i = (b - A_BLOCKS) * 256 + t;  // half8 index
        float4 v0 = ((const float4*)x)[i * 2];
        float4 v1 = ((const float4*)x)[i * 2 + 1];
        half8 o = {(_Float16)v0.x, (_Float16)v0.y, (_Float16)v0.z, (_Float16)v0.w,
                   (_Float16)v1.x, (_Float16)v1.y, (_Float16)v1.z, (_Float16)v1.w};
        ((half8*)x16)[i] = o;
    } else if (b < A_BLOCKS + CVT_BLOCKS + WT1_BLOCKS) {
        int n = b - A_BLOCKS - CVT_BLOCKS;
        if (t < IN_CH) W1T[(size_t)n * IN_CH + t] = (_Float16)W1[(size_t)t * HID_CH + n];
    } else {
        int n = b - A_BLOCKS - CVT_BLOCKS - WT1_BLOCKS;
        if (t < HID_CH) W2T[(size_t)n * HID_CH + t] = (_Float16)W2[(size_t)t * OUT_CH + n];
    }
}

__global__ __launch_bounds__(256) void prepB_kernel(const int* __restrict__ bin_fill,
                                                    const unsigned int* __restrict__ binbuf,
                                                    int* __restrict__ cnt,
                                                    unsigned short* __restrict__ bucket) {
    __shared__ int lcnt[NPB];
    __shared__ __align__(16) unsigned short lbk[NPB][BUCKET];  // 16 KB staging
    int bin = blockIdx.x, t = threadIdx.x;
    if (t < NPB) lcnt[t] = 0;
    for (int q = t; q < NPB * BUCKET / 8; q += 256)
        ((uint4*)lbk)[q] = make_uint4(0u, 0u, 0u, 0u);  // empty slots -> src 0 (NaN-safe)
    __syncthreads();
    int n = min(bin_fill[bin], BIN_CAP);
    for (int i = t; i < n; i += 256) {
        unsigned e = binbuf[(size_t)bin * BIN_CAP + i];
        int dl = e >> 16;
        int s = e & 0xFFFF;
        int p = atomicAdd(&lcnt[dl], 1);
        if (p < BUCKET) lbk[dl][p] = (unsigned short)s;
    }
    __syncthreads();
    // stream bucket rows out coalesced: 128 rows x 128 B = 1024 uint4
    const uint4* lp = (const uint4*)lbk;
    uint4* gp = (uint4*)(bucket + (size_t)bin * NPB * BUCKET);
    for (int q = t; q < NPB * BUCKET / 8; q += 256) {
        int row = q >> 3;  // 8 uint4 per 64-slot row
        if (bin * NPB + row < N_NODES) gp[q] = lp[q];
    }
    int v = bin * NPB + t;
    if (t < NPB && v < N_NODES) cnt[v] = lcnt[t];
}

// ---------------- aggregation (fp16 features, 128 ch) ----------------
// 16 lanes per node, 8 ch per lane; neighbor ids broadcast via shfl(width=16).
// R5: full-chunk pipelining — all 16 shfl+gathers issued before any FMA, so a
// wave keeps 16 vector loads (4KB) in flight instead of 8. Targets the measured
// ~4.2 TB/s effective gather rate (if partially latency-starved at L3 ~900cy).
// Dummy lanes (idx >= deg) force a=0 BEFORE the gather and w=0 (NaN-safe).

template <bool OUT16>
__global__ __launch_bounds__(256) void agg16_kernel(const _Float16* __restrict__ h16,
                                                    const int* __restrict__ cnt,
                                                    const unsigned short* __restrict__ bucket,
                                                    const float* __restrict__ bias,
                                                    void* __restrict__ outp) {
    int t = blockIdx.x * 256 + threadIdx.x;
    int v = t >> 4;      // node (grid sized exactly: 50000*16/256 blocks)
    int sub = t & 15;    // lane group index
    int degr = cnt[v];
    int deg = min(degr, BUCKET);  // loop bound (UB guard; real max deg ~35)
    float dv = rsqrtf((float)degr + 1.0f);
    half8 hv = ((const half8*)(h16 + (size_t)v * 128))[sub];
    float acc[8];
#pragma unroll
    for (int i = 0; i < 8; i++) acc[i] = (float)hv[i] * dv * dv;  // self-loop

    const unsigned short* bk = bucket + (size_t)v * BUCKET;
    for (int base = 0; base < deg; base += 16) {
        int idx = base + sub;
        int am = (int)bk[min(idx, BUCKET - 1)];  // in-row clamp; content may be stale
        bool ok = idx < deg;
        int a = ok ? am : 0;                     // mask BEFORE gather (NaN-safe)
        float c = ok ? rsqrtf((float)cnt[a] + 1.0f) * dv : 0.f;

        int   s[16];
        float w[16];
        half8 xv[16];
#pragma unroll
        for (int j = 0; j < 16; j++) {
            s[j] = __shfl(a, j, 16);
            w[j] = __shfl(c, j, 16);
        }
#pragma unroll
        for (int j = 0; j < 16; j++)
            xv[j] = ((const half8*)(h16 + (size_t)s[j] * 128))[sub];  // 16 loads in flight
#pragma unroll
        for (int j = 0; j < 16; j++)
#pragma unroll
            for (int i = 0; i < 8; i++) acc[i] += w[j] * (float)xv[j][i];
    }

    if (OUT16) {
        half8 o;
#pragma unroll
        for (int i = 0; i < 8; i++) o[i] = (_Float16)acc[i];
        ((half8*)outp)[(size_t)v * 16 + sub] = o;
    } else {
        const float4* bp = (const float4*)bias;
        float4 b0 = bp[sub * 2], b1v = bp[sub * 2 + 1];
        float4 o0 = make_float4(acc[0] + b0.x, acc[1] + b0.y, acc[2] + b0.z, acc[3] + b0.w);
        float4 o1 = make_float4(acc[4] + b1v.x, acc[5] + b1v.y, acc[6] + b1v.z, acc[7] + b1v.w);
        float4* op = (float4*)outp;
        op[(size_t)v * 32 + sub * 2] = o0;
        op[(size_t)v * 32 + sub * 2 + 1] = o1;
    }
}

// ---------------- fused MLP: t2 = relu(a1 @ W1 + b1) @ W2, fp16 in/out ----------------
// W1T/W2T are 64 KB each and L2-resident -> B fragments loaded per-wave directly
// from global (no Bs staging, 3 barriers/block). LDS = 50 KB -> 3 blocks/CU.

__global__ __launch_bounds__(256) void fused_mlp_kernel(const _Float16* __restrict__ A,
                                                        const _Float16* __restrict__ W1T,
                                                        const float* __restrict__ b1,
                                                        const _Float16* __restrict__ W2T,
                                                        _Float16* __restrict__ T2, int M) {
    const int LDH = 264;  // h1s row stride (256+8): row step = 4 banks -> 2-way only (free)
    const int LDA = 136;  // As/Cs row stride (128+8)
    __shared__ __align__(16) _Float16 h1s[64 * LDH];  // 33792 B
    __shared__ __align__(16) _Float16 As[64 * LDA];   // 17408 B; reused as Cs in epilogue

    int tid = threadIdx.x;
    int wave = tid >> 6, lane = tid & 63;
    int quad = lane >> 4, l16 = lane & 15;
    int wm = wave >> 1, wn = wave & 1;
    int bm = blockIdx.x * 64;

    // stage full A tile: 64 rows x 128 fp16
    for (int q = tid; q < 64 * 16; q += 256) {
        int row = q >> 4, seg = q & 15;
        int gr = bm + row;
        float4 v = make_float4(0.f, 0.f, 0.f, 0.f);
        if (gr < M) v = *(const float4*)(A + (size_t)gr * IN_CH + seg * 8);
        *(float4*)(As + row * LDA + seg * 8) = v;
    }
    __syncthreads();

    // ---- phase 1: h1 = relu(A @ W1T^T + b1), two N-halves of 128, no barriers ----
    for (int nh = 0; nh < 2; nh++) {
        f32x4 acc[2][4] = {};
#pragma unroll
        for (int k0 = 0; k0 < IN_CH; k0 += 32) {
            half8 af[2], bf[4];
#pragma unroll
            for (int nt = 0; nt < 4; nt++)
                bf[nt] = *(const half8*)(W1T + (size_t)(nh * 128 + wn * 64 + nt * 16 + l16) * IN_CH +
                                         k0 + quad * 8);
#pragma unroll
            for (int mt = 0; mt < 2; mt++)
                af[mt] = *(const half8*)(As + (wm * 32 + mt * 16 + l16) * LDA + k0 + quad * 8);
#pragma unroll
            for (int mt = 0; mt < 2; mt++)
#pragma unroll
                for (int nt = 0; nt < 4; nt++)
                    acc[mt][nt] = __builtin_amdgcn_mfma_f32_16x16x32_f16(af[mt], bf[nt], acc[mt][nt], 0, 0, 0);
        }
        // epilogue half -> h1s (relu + b1)
#pragma unroll
        for (int mt = 0; mt < 2; mt++)
#pragma unroll
            for (int nt = 0; nt < 4; nt++)
#pragma unroll
                for (int r = 0; r < 4; r++) {
                    int ml = wm * 32 + mt * 16 + quad * 4 + r;
                    int nl = wn * 64 + nt * 16 + l16;
                    float v = acc[mt][nt][r] + b1[nh * 128 + nl];
                    h1s[ml * LDH + nh * 128 + nl] = (_Float16)fmaxf(v, 0.f);
                }
    }
    __syncthreads();  // h1s complete before phase-2 reads

    // ---- phase 2: t2 = h1 @ W2T^T (K = 256: A from LDS, B from global) ----
    f32x4 acc2[2][4] = {};
#pragma unroll 4
    for (int k0 = 0; k0 < HID_CH; k0 += 32) {
        half8 af[2], bf[4];
#pragma unroll
        for (int nt = 0; nt < 4; nt++)
            bf[nt] = *(const half8*)(W2T + (size_t)(wn * 64 + nt * 16 + l16) * HID_CH + k0 + quad * 8);
#pragma unroll
        for (int mt = 0; mt < 2; mt++)
            af[mt] = *(const half8*)(h1s + (wm * 32 + mt * 16 + l16) * LDH + k0 + quad * 8);
#pragma unroll
        for (int mt = 0; mt < 2; mt++)
#pragma unroll
            for (int nt = 0; nt < 4; nt++)
                acc2[mt][nt] = __builtin_amdgcn_mfma_f32_16x16x32_f16(af[mt], bf[nt], acc2[mt][nt], 0, 0, 0);
    }

    // epilogue: t2 via Cs (= As region, free after phase 1) for coalesced fp16 stores
    _Float16* Cs = As;
#pragma unroll
    for (int mt = 0; mt < 2; mt++)
#pragma unroll
        for (int nt = 0; nt < 4; nt++)
#pragma unroll
            for (int r = 0; r < 4; r++) {
                int ml = wm * 32 + mt * 16 + quad * 4 + r;
                int nl = wn * 64 + nt * 16 + l16;
                Cs[ml * LDA + nl] = (_Float16)acc2[mt][nt][r];
            }
    __syncthreads();
    for (int q = tid; q < 64 * 16; q += 256) {
        int row = q >> 4, seg = q & 15;
        int gr = bm + row;
        if (gr < M)
            *(float4*)(T2 + (size_t)gr * OUT_CH + seg * 8) = *(const float4*)(Cs + row * LDA + seg * 8);
    }
}

// ---------------- launch ----------------

extern "C" void kernel_launch(void* const* d_in, const int* in_sizes, int n_in,
                              void* d_out, int out_size, void* d_ws, size_t ws_size,
                              hipStream_t stream) {
    const float* x  = (const float*)d_in[0];
    const int*   ei = (const int*)d_in[1];
    const int*   src = ei;
    const int*   dst = ei + N_EDGES;
    const float* W1 = (const float*)d_in[2];
    const float* b1 = (const float*)d_in[3];
    const float* W2 = (const float*)d_in[4];
    const float* b2 = (const float*)d_in[5];
    float* out = (float*)d_out;

    char* w = (char*)d_ws;
    auto alloc = [&](size_t bytes) -> void* {
        void* p = (void*)w;
        w += (bytes + 255) & ~(size_t)255;
        return p;
    };
    int*            cnt     = (int*)alloc((size_t)N_NODES * 4);
    unsigned short* bucket  = (unsigned short*)alloc((size_t)N_NODES * BUCKET * 2);
    _Float16*       x16     = (_Float16*)alloc((size_t)N_NODES * IN_CH * 2);
    _Float16*       a1      = (_Float16*)alloc((size_t)N_NODES * IN_CH * 2);
    _Float16*       t2      = (_Float16*)alloc((size_t)N_NODES * OUT_CH * 2);
    _Float16*       W1T     = (_Float16*)alloc((size_t)IN_CH * HID_CH * 2);
    _Float16*       W2T     = (_Float16*)alloc((size_t)HID_CH * OUT_CH * 2);
    int*            bin_fill = (int*)alloc((size_t)NB * 4);
    unsigned int*   binbuf   = (unsigned int*)alloc((size_t)NB * BIN_CAP * 4);

    hipMemsetAsync(bin_fill, 0, (size_t)NB * 4, stream);

    // phase A: radix-partition edges into 391 bins (+ x->fp16 cvt + W transposes)
    prepA_kernel<<<A_BLOCKS + CVT_BLOCKS + WT1_BLOCKS + WT2_BLOCKS, 256, 0, stream>>>(
        src, dst, bin_fill, binbuf, x, x16, W1, W1T, W2, W2T);
    // phase B: per-bin bucket build, LDS-staged rows -> coalesced uint4 stores
    prepB_kernel<<<NB, 256, 0, stream>>>(bin_fill, binbuf, cnt, bucket);

    // layer 1 aggregate: a1 = Â x
    agg16_kernel<true><<<N_NODES * 16 / 256, 256, 0, stream>>>(x16, cnt, bucket, nullptr, a1);
    // fused MLP: t2 = relu(a1 @ W1 + b1) @ W2
    fused_mlp_kernel<<<(N_NODES + 63) / 64, 256, 0, stream>>>(a1, W1T, b1, W2T, t2, N_NODES);
    // layer 2 aggregate: out = Â t2 + b2
    agg16_kernel<false><<<N_NODES * 16 / 256, 256, 0, stream>>>(t2, cnt, bucket, b2, out);
}

// Round 6
// 205.802 us; speedup vs baseline: 1.0579x; 1.0427x over previous
//
#include <hip/hip_runtime.h>

#define N_NODES 50000
#define N_EDGES 800000
#define IN_CH 128
#define HID_CH 256
#define OUT_CH 128
#define BUCKET 64  // max degree slot count; P(deg>64) ~ e^-40 for Poisson(16)

using half8 = __attribute__((ext_vector_type(8))) _Float16;
using f32x4 = __attribute__((ext_vector_type(4))) float;

// ---------------- two-phase radix-partition bucket build ----------------
// Phase A: block-local LDS histogram over 391 bins (bin = dst>>7, 128 nodes/bin),
//          ONE global atomic per (block,bin) to reserve space, scatter packed
//          (src | dlocal<<16) into bin segments.
// Phase B: one block per bin; slot assignment via LDS atomicAdd (on-CU); bucket
//          rows assembled in LDS and streamed out as coalesced uint4 stores.
// Session evidence (R4/R5): agg is BYTES-bound on the random 256B/edge feature
// gather (~205MB/layer from L3 at ~5 TB/s effective). Extra streams (+50MB ->
// +12us, R4) and deeper gather pipelining (VGPR pressure, R5) both hurt.
// This is the best-measured configuration (R3: 206us; family floor ~205).

#define NB 391        // bins = ceil(50000/128); 49999>>7 = 390
#define NPB 128       // nodes per bin
#define BIN_CAP 2432  // per-bin record capacity: mu=2048, sigma~45 -> mu+8.5sigma
#define A_CHUNK 4096  // edges per phase-A block
#define A_BLOCKS 196  // ceil(800000/4096)

#define CVT_BLOCKS 3125  // 50000*128/8 half8 items / 256
#define WT1_BLOCKS 256   // HID_CH rows of W1T
#define WT2_BLOCKS 128   // OUT_CH rows of W2T

__global__ __launch_bounds__(256) void prepA_kernel(const int* __restrict__ src,
                                                    const int* __restrict__ dst,
                                                    int* __restrict__ bin_fill,
                                                    unsigned int* __restrict__ binbuf,
                                                    const float* __restrict__ x,
                                                    _Float16* __restrict__ x16,
                                                    const float* __restrict__ W1,
                                                    _Float16* __restrict__ W1T,
                                                    const float* __restrict__ W2,
                                                    _Float16* __restrict__ W2T) {
    __shared__ int hist[NB];
    __shared__ int lbase[NB];
    __shared__ int cur[NB];
    int b = blockIdx.x, t = threadIdx.x;
    if (b < A_BLOCKS) {
        for (int i = t; i < NB; i += 256) {
            hist[i] = 0;
            cur[i] = 0;
        }
        __syncthreads();
        int e0 = b * A_CHUNK;
        int d[16];
#pragma unroll
        for (int k = 0; k < 16; k++) {
            int i = e0 + k * 256 + t;
            d[k] = (i < N_EDGES) ? dst[i] : -1;
            if (d[k] >= 0) atomicAdd(&hist[d[k] >> 7], 1);
        }
        __syncthreads();
        for (int i = t; i < NB; i += 256)
            if (hist[i]) lbase[i] = atomicAdd(&bin_fill[i], hist[i]);
        __syncthreads();
#pragma unroll
        for (int k = 0; k < 16; k++) {
            int i = e0 + k * 256 + t;
            if (d[k] >= 0) {
                int bin = d[k] >> 7;
                int s = src[i];
                int o = atomicAdd(&cur[bin], 1);
                int pos = lbase[bin] + o;
                if (pos < BIN_CAP)
                    binbuf[(size_t)bin * BIN_CAP + pos] =
                        (unsigned)s | ((unsigned)(d[k] & (NPB - 1)) << 16);
            }
        }
    } else if (b < A_BLOCKS + CVT_BLOCKS) {
        int i = (b - A_BLOCKS) * 256 + t;  // half8 index
        float4 v0 = ((const float4*)x)[i * 2];
        float4 v1 = ((const float4*)x)[i * 2 + 1];
        half8 o = {(_Float16)v0.x, (_Float16)v0.y, (_Float16)v0.z, (_Float16)v0.w,
                   (_Float16)v1.x, (_Float16)v1.y, (_Float16)v1.z, (_Float16)v1.w};
        ((half8*)x16)[i] = o;
    } else if (b < A_BLOCKS + CVT_BLOCKS + WT1_BLOCKS) {
        int n = b - A_BLOCKS - CVT_BLOCKS;
        if (t < IN_CH) W1T[(size_t)n * IN_CH + t] = (_Float16)W1[(size_t)t * HID_CH + n];
    } else {
        int n = b - A_BLOCKS - CVT_BLOCKS - WT1_BLOCKS;
        if (t < HID_CH) W2T[(size_t)n * HID_CH + t] = (_Float16)W2[(size_t)t * OUT_CH + n];
    }
}

__global__ __launch_bounds__(256) void prepB_kernel(const int* __restrict__ bin_fill,
                                                    const unsigned int* __restrict__ binbuf,
                                                    int* __restrict__ cnt,
                                                    unsigned short* __restrict__ bucket) {
    __shared__ int lcnt[NPB];
    __shared__ __align__(16) unsigned short lbk[NPB][BUCKET];  // 16 KB staging
    int bin = blockIdx.x, t = threadIdx.x;
    if (t < NPB) lcnt[t] = 0;
    for (int q = t; q < NPB * BUCKET / 8; q += 256)
        ((uint4*)lbk)[q] = make_uint4(0u, 0u, 0u, 0u);  // empty slots -> src 0 (NaN-safe)
    __syncthreads();
    int n = min(bin_fill[bin], BIN_CAP);
    for (int i = t; i < n; i += 256) {
        unsigned e = binbuf[(size_t)bin * BIN_CAP + i];
        int dl = e >> 16;
        int s = e & 0xFFFF;
        int p = atomicAdd(&lcnt[dl], 1);
        if (p < BUCKET) lbk[dl][p] = (unsigned short)s;
    }
    __syncthreads();
    // stream bucket rows out coalesced: 128 rows x 128 B = 1024 uint4
    const uint4* lp = (const uint4*)lbk;
    uint4* gp = (uint4*)(bucket + (size_t)bin * NPB * BUCKET);
    for (int q = t; q < NPB * BUCKET / 8; q += 256) {
        int row = q >> 3;  // 8 uint4 per 64-slot row
        if (bin * NPB + row < N_NODES) gp[q] = lp[q];
    }
    int v = bin * NPB + t;
    if (t < NPB && v < N_NODES) cnt[v] = lcnt[t];
}

// ---------------- aggregation (fp16 features, 128 ch) ----------------
// 16 lanes per node, 8 ch per lane; neighbor ids broadcast via shfl(width=16).
// Branch-free inner loop: always two masked 8-wide rounds per 16-chunk (8 gathers
// in flight; 16-deep variant regressed via VGPR pressure, R5). Dummy lanes
// (idx >= deg) force a=0 BEFORE the gather and w=0, so garbage slots are inert.

template <bool OUT16>
__global__ __launch_bounds__(256) void agg16_kernel(const _Float16* __restrict__ h16,
                                                    const int* __restrict__ cnt,
                                                    const unsigned short* __restrict__ bucket,
                                                    const float* __restrict__ bias,
                                                    void* __restrict__ outp) {
    int t = blockIdx.x * 256 + threadIdx.x;
    int v = t >> 4;      // node (grid sized exactly: 50000*16/256 blocks)
    int sub = t & 15;    // lane group index
    int degr = cnt[v];
    int deg = min(degr, BUCKET);  // loop bound (UB guard; real max deg ~35)
    float dv = rsqrtf((float)degr + 1.0f);
    half8 hv = ((const half8*)(h16 + (size_t)v * 128))[sub];
    float acc[8];
#pragma unroll
    for (int i = 0; i < 8; i++) acc[i] = (float)hv[i] * dv * dv;  // self-loop

#define PROCESS8(J)                                                                   \
    {                                                                                 \
        int   s0 = __shfl(a, (J) + 0, 16); float w0 = __shfl(c, (J) + 0, 16);         \
        int   s1 = __shfl(a, (J) + 1, 16); float w1 = __shfl(c, (J) + 1, 16);         \
        int   s2 = __shfl(a, (J) + 2, 16); float w2 = __shfl(c, (J) + 2, 16);         \
        int   s3 = __shfl(a, (J) + 3, 16); float w3 = __shfl(c, (J) + 3, 16);         \
        int   s4 = __shfl(a, (J) + 4, 16); float w4 = __shfl(c, (J) + 4, 16);         \
        int   s5 = __shfl(a, (J) + 5, 16); float w5 = __shfl(c, (J) + 5, 16);         \
        int   s6 = __shfl(a, (J) + 6, 16); float w6 = __shfl(c, (J) + 6, 16);         \
        int   s7 = __shfl(a, (J) + 7, 16); float w7 = __shfl(c, (J) + 7, 16);         \
        half8 x0 = ((const half8*)(h16 + (size_t)s0 * 128))[sub];                     \
        half8 x1 = ((const half8*)(h16 + (size_t)s1 * 128))[sub];                     \
        half8 x2 = ((const half8*)(h16 + (size_t)s2 * 128))[sub];                     \
        half8 x3 = ((const half8*)(h16 + (size_t)s3 * 128))[sub];                     \
        half8 x4 = ((const half8*)(h16 + (size_t)s4 * 128))[sub];                     \
        half8 x5 = ((const half8*)(h16 + (size_t)s5 * 128))[sub];                     \
        half8 x6 = ((const half8*)(h16 + (size_t)s6 * 128))[sub];                     \
        half8 x7 = ((const half8*)(h16 + (size_t)s7 * 128))[sub];                     \
        _Pragma("unroll") for (int i = 0; i < 8; i++) acc[i] += w0 * (float)x0[i];    \
        _Pragma("unroll") for (int i = 0; i < 8; i++) acc[i] += w1 * (float)x1[i];    \
        _Pragma("unroll") for (int i = 0; i < 8; i++) acc[i] += w2 * (float)x2[i];    \
        _Pragma("unroll") for (int i = 0; i < 8; i++) acc[i] += w3 * (float)x3[i];    \
        _Pragma("unroll") for (int i = 0; i < 8; i++) acc[i] += w4 * (float)x4[i];    \
        _Pragma("unroll") for (int i = 0; i < 8; i++) acc[i] += w5 * (float)x5[i];    \
        _Pragma("unroll") for (int i = 0; i < 8; i++) acc[i] += w6 * (float)x6[i];    \
        _Pragma("unroll") for (int i = 0; i < 8; i++) acc[i] += w7 * (float)x7[i];    \
    }

    const unsigned short* bk = bucket + (size_t)v * BUCKET;
    for (int base = 0; base < deg; base += 16) {
        int idx = base + sub;
        int am = (int)bk[min(idx, BUCKET - 1)];  // in-row clamp; content may be garbage
        bool ok = idx < deg;
        int a = ok ? am : 0;                     // mask BEFORE gather (NaN-safe)
        float c = ok ? rsqrtf((float)cnt[a] + 1.0f) * dv : 0.f;
        PROCESS8(0)
        if (base + 8 < deg) PROCESS8(8)
    }
#undef PROCESS8

    if (OUT16) {
        half8 o;
#pragma unroll
        for (int i = 0; i < 8; i++) o[i] = (_Float16)acc[i];
        ((half8*)outp)[(size_t)v * 16 + sub] = o;
    } else {
        const float4* bp = (const float4*)bias;
        float4 b0 = bp[sub * 2], b1v = bp[sub * 2 + 1];
        float4 o0 = make_float4(acc[0] + b0.x, acc[1] + b0.y, acc[2] + b0.z, acc[3] + b0.w);
        float4 o1 = make_float4(acc[4] + b1v.x, acc[5] + b1v.y, acc[6] + b1v.z, acc[7] + b1v.w);
        float4* op = (float4*)outp;
        op[(size_t)v * 32 + sub * 2] = o0;
        op[(size_t)v * 32 + sub * 2 + 1] = o1;
    }
}

// ---------------- fused MLP: t2 = relu(a1 @ W1 + b1) @ W2, fp16 in/out ----------------
// W1T/W2T are 64 KB each and L2-resident -> B fragments loaded per-wave directly
// from global (no Bs staging, 3 barriers/block). LDS = 50 KB -> 3 blocks/CU.

__global__ __launch_bounds__(256) void fused_mlp_kernel(const _Float16* __restrict__ A,
                                                        const _Float16* __restrict__ W1T,
                                                        const float* __restrict__ b1,
                                                        const _Float16* __restrict__ W2T,
                                                        _Float16* __restrict__ T2, int M) {
    const int LDH = 264;  // h1s row stride (256+8): row step = 4 banks -> 2-way only (free)
    const int LDA = 136;  // As/Cs row stride (128+8)
    __shared__ __align__(16) _Float16 h1s[64 * LDH];  // 33792 B
    __shared__ __align__(16) _Float16 As[64 * LDA];   // 17408 B; reused as Cs in epilogue

    int tid = threadIdx.x;
    int wave = tid >> 6, lane = tid & 63;
    int quad = lane >> 4, l16 = lane & 15;
    int wm = wave >> 1, wn = wave & 1;
    int bm = blockIdx.x * 64;

    // stage full A tile: 64 rows x 128 fp16
    for (int q = tid; q < 64 * 16; q += 256) {
        int row = q >> 4, seg = q & 15;
        int gr = bm + row;
        float4 v = make_float4(0.f, 0.f, 0.f, 0.f);
        if (gr < M) v = *(const float4*)(A + (size_t)gr * IN_CH + seg * 8);
        *(float4*)(As + row * LDA + seg * 8) = v;
    }
    __syncthreads();

    // ---- phase 1: h1 = relu(A @ W1T^T + b1), two N-halves of 128, no barriers ----
    for (int nh = 0; nh < 2; nh++) {
        f32x4 acc[2][4] = {};
#pragma unroll
        for (int k0 = 0; k0 < IN_CH; k0 += 32) {
            half8 af[2], bf[4];
#pragma unroll
            for (int nt = 0; nt < 4; nt++)
                bf[nt] = *(const half8*)(W1T + (size_t)(nh * 128 + wn * 64 + nt * 16 + l16) * IN_CH +
                                         k0 + quad * 8);
#pragma unroll
            for (int mt = 0; mt < 2; mt++)
                af[mt] = *(const half8*)(As + (wm * 32 + mt * 16 + l16) * LDA + k0 + quad * 8);
#pragma unroll
            for (int mt = 0; mt < 2; mt++)
#pragma unroll
                for (int nt = 0; nt < 4; nt++)
                    acc[mt][nt] = __builtin_amdgcn_mfma_f32_16x16x32_f16(af[mt], bf[nt], acc[mt][nt], 0, 0, 0);
        }
        // epilogue half -> h1s (relu + b1)
#pragma unroll
        for (int mt = 0; mt < 2; mt++)
#pragma unroll
            for (int nt = 0; nt < 4; nt++)
#pragma unroll
                for (int r = 0; r < 4; r++) {
                    int ml = wm * 32 + mt * 16 + quad * 4 + r;
                    int nl = wn * 64 + nt * 16 + l16;
                    float v = acc[mt][nt][r] + b1[nh * 128 + nl];
                    h1s[ml * LDH + nh * 128 + nl] = (_Float16)fmaxf(v, 0.f);
                }
    }
    __syncthreads();  // h1s complete before phase-2 reads

    // ---- phase 2: t2 = h1 @ W2T^T (K = 256: A from LDS, B from global) ----
    f32x4 acc2[2][4] = {};
#pragma unroll 4
    for (int k0 = 0; k0 < HID_CH; k0 += 32) {
        half8 af[2], bf[4];
#pragma unroll
        for (int nt = 0; nt < 4; nt++)
            bf[nt] = *(const half8*)(W2T + (size_t)(wn * 64 + nt * 16 + l16) * HID_CH + k0 + quad * 8);
#pragma unroll
        for (int mt = 0; mt < 2; mt++)
            af[mt] = *(const half8*)(h1s + (wm * 32 + mt * 16 + l16) * LDH + k0 + quad * 8);
#pragma unroll
        for (int mt = 0; mt < 2; mt++)
#pragma unroll
            for (int nt = 0; nt < 4; nt++)
                acc2[mt][nt] = __builtin_amdgcn_mfma_f32_16x16x32_f16(af[mt], bf[nt], acc2[mt][nt], 0, 0, 0);
    }

    // epilogue: t2 via Cs (= As region, free after phase 1) for coalesced fp16 stores
    _Float16* Cs = As;
#pragma unroll
    for (int mt = 0; mt < 2; mt++)
#pragma unroll
        for (int nt = 0; nt < 4; nt++)
#pragma unroll
            for (int r = 0; r < 4; r++) {
                int ml = wm * 32 + mt * 16 + quad * 4 + r;
                int nl = wn * 64 + nt * 16 + l16;
                Cs[ml * LDA + nl] = (_Float16)acc2[mt][nt][r];
            }
    __syncthreads();
    for (int q = tid; q < 64 * 16; q += 256) {
        int row = q >> 4, seg = q & 15;
        int gr = bm + row;
        if (gr < M)
            *(float4*)(T2 + (size_t)gr * OUT_CH + seg * 8) = *(const float4*)(Cs + row * LDA + seg * 8);
    }
}

// ---------------- launch ----------------

extern "C" void kernel_launch(void* const* d_in, const int* in_sizes, int n_in,
                              void* d_out, int out_size, void* d_ws, size_t ws_size,
                              hipStream_t stream) {
    const float* x  = (const float*)d_in[0];
    const int*   ei = (const int*)d_in[1];
    const int*   src = ei;
    const int*   dst = ei + N_EDGES;
    const float* W1 = (const float*)d_in[2];
    const float* b1 = (const float*)d_in[3];
    const float* W2 = (const float*)d_in[4];
    const float* b2 = (const float*)d_in[5];
    float* out = (float*)d_out;

    char* w = (char*)d_ws;
    auto alloc = [&](size_t bytes) -> void* {
        void* p = (void*)w;
        w += (bytes + 255) & ~(size_t)255;
        return p;
    };
    int*            cnt     = (int*)alloc((size_t)N_NODES * 4);
    unsigned short* bucket  = (unsigned short*)alloc((size_t)N_NODES * BUCKET * 2);
    _Float16*       x16     = (_Float16*)alloc((size_t)N_NODES * IN_CH * 2);
    _Float16*       a1      = (_Float16*)alloc((size_t)N_NODES * IN_CH * 2);
    _Float16*       t2      = (_Float16*)alloc((size_t)N_NODES * OUT_CH * 2);
    _Float16*       W1T     = (_Float16*)alloc((size_t)IN_CH * HID_CH * 2);
    _Float16*       W2T     = (_Float16*)alloc((size_t)HID_CH * OUT_CH * 2);
    int*            bin_fill = (int*)alloc((size_t)NB * 4);
    unsigned int*   binbuf   = (unsigned int*)alloc((size_t)NB * BIN_CAP * 4);

    hipMemsetAsync(bin_fill, 0, (size_t)NB * 4, stream);

    // phase A: radix-partition edges into 391 bins (+ x->fp16 cvt + W transposes)
    prepA_kernel<<<A_BLOCKS + CVT_BLOCKS + WT1_BLOCKS + WT2_BLOCKS, 256, 0, stream>>>(
        src, dst, bin_fill, binbuf, x, x16, W1, W1T, W2, W2T);
    // phase B: per-bin bucket build, LDS-staged rows -> coalesced uint4 stores
    prepB_kernel<<<NB, 256, 0, stream>>>(bin_fill, binbuf, cnt, bucket);

    // layer 1 aggregate: a1 = Â x
    agg16_kernel<true><<<N_NODES * 16 / 256, 256, 0, stream>>>(x16, cnt, bucket, nullptr, a1);
    // fused MLP: t2 = relu(a1 @ W1 + b1) @ W2
    fused_mlp_kernel<<<(N_NODES + 63) / 64, 256, 0, stream>>>(a1, W1T, b1, W2T, t2, N_NODES);
    // layer 2 aggregate: out = Â t2 + b2
    agg16_kernel<false><<<N_NODES * 16 / 256, 256, 0, stream>>>(t2, cnt, bucket, b2, out);
}